// Round 3
// baseline (280.797 us; speedup 1.0000x reference)
//
#include <hip/hip_runtime.h>

// CompanionSSM, 4-kernel chunked state-space decomposition (C=64):
//   prep : per-head G(128x128,bf16) = [[W, ToepK],[T, V]]  (ws[0, 8MB))
//   K2   : R_q = V@U_q  for all (h,q)            -> RS slots (ws[8MB, 40MB))
//   K3   : serial per-head scan S_{q+1}=T@S_q+R_q, 1 wave/head, NO barriers;
//          stores S_q as bf16 B-frags in-place over R slot (h,q)
//   K4   : Y_q = W@S_q + Toep@U_q, barrier-free, coalesced out
// Requires ws_size >= 40 MB.

#define NKH 256
#define KD  64
#define SL  4096
#define DM  1024
#define NCHUNK 64

typedef __attribute__((ext_vector_type(8))) short short8;
typedef __attribute__((ext_vector_type(4))) float floatx4;

// pack two floats to bf16 pair (round-half-up): lo16 = a, hi16 = b
static __device__ __forceinline__ unsigned pack_bf16(float a, float b) {
  union { float f; unsigned u; } ua, ub;
  ua.f = a; ub.f = b;
  return __builtin_amdgcn_perm(ub.u + 0x8000u, ua.u + 0x8000u, 0x07060302u);
}
static __device__ __forceinline__ unsigned short f2bfru(float x) {
  union { float f; unsigned u; } v; v.f = x;
  return (unsigned short)((v.u + 0x8000u) >> 16);
}
static __device__ __forceinline__ float bflo(unsigned d) {
  union { unsigned u; float f; } v; v.u = d << 16; return v.f;
}
static __device__ __forceinline__ float bfhi(unsigned d) {
  union { unsigned u; float f; } v; v.u = d & 0xffff0000u; return v.f;
}

// ---------------------------------------------------------------- prep ----
// 2 waves/head. g_p = A^p e_0:  T[:,m]=g_{64+m};  W[j][i]=phi[j+1+i], phi_p=c.g_p.
__global__ __launch_bounds__(128) void prep_kernel(
    const float* __restrict__ ga, const float* __restrict__ gb,
    const float* __restrict__ gc, unsigned short* __restrict__ gw)
{
  __shared__ unsigned short G[128 * 128];   // 32 KB
  __shared__ float phi[128];
  __shared__ float kv2[KD];

  const int h = blockIdx.x;
  const int t = threadIdx.x;
  const int wv = t >> 6;
  const int i = t & 63;

  const float av = ga[h*KD + i];
  float nrm = fabsf(av);
#pragma unroll
  for (int off = 32; off; off >>= 1) nrm += __shfl_xor(nrm, off, 64);
  const float an = av / nrm;   // mean(|rowsum|) >> eps for N(0,1) inputs
  const float bv = gb[h*KD + i];
  const float cv = gc[h*KD + i];

  if (wv == 0) {
    // v-chain: v_j = A^j b -> V block G[64+i][64+63-j]; k[j] = c.v_j
    float v = bv;
    for (int j = 0; j < KD; ++j) {
      float d = cv * v;
#pragma unroll
      for (int off = 32; off; off >>= 1) d += __shfl_xor(d, off, 64);
      if (i == 0) kv2[j] = d;
      G[(64+i)*128 + 64 + (63-j)] = f2bfru(v);
      const float top = __shfl(v, KD-1, 64);
      const float vm1 = __shfl_up(v, 1, 64);
      v = (i > 0 ? vm1 : 0.0f) + an * top;
    }
  } else {
    phi[i] = cv;               // phi_p = c_p for p < 64
    // g-chain: g_64 = a_n; T col m = g_{64+m}; phi_p = c.g_p
    float g = an;
    for (int p = 64; p < 128; ++p) {
      G[(64+i)*128 + (p-64)] = f2bfru(g);
      float d = cv * g;
#pragma unroll
      for (int off = 32; off; off >>= 1) d += __shfl_xor(d, off, 64);
      if (i == 0) phi[p] = d;
      const float top = __shfl(g, KD-1, 64);
      const float gm1 = __shfl_up(g, 1, 64);
      g = (i > 0 ? gm1 : 0.0f) + an * top;
    }
  }
  __syncthreads();

  // W block: G[j][i] = phi[j+1+i]
  for (int idx = t; idx < 4096; idx += 128) {
    const int j = idx >> 6, ii = idx & 63;
    G[j*128 + ii] = f2bfru(phi[j + 1 + ii]);
  }
  // Toeplitz block: G[i][64+m] = (m<=i) ? k[i-m] : 0
  for (int idx = t; idx < 4096; idx += 128) {
    const int ii = idx >> 6, m = idx & 63;
    G[ii*128 + 64 + m] = (m <= ii) ? f2bfru(kv2[ii-m]) : (unsigned short)0;
  }
  __syncthreads();

  const int4* src = (const int4*)G;
  int4* dst = (int4*)(gw + (size_t)h * 16384);
  for (int idx = t; idx < 2048; idx += 128) dst[idx] = src[idx];
}

// ------------------------------------------------------------- K2: R ----
// Block: head h, 16 chunks; wave w: 4 chunks. Barrier-free (wave-private LDS).
__global__ __launch_bounds__(256) void partial_kernel(
    const float* __restrict__ u, const unsigned short* __restrict__ G,
    char* __restrict__ RS)
{
  __shared__ unsigned short X2[4][64*20];   // per-wave [row 64][col 16], pad 20

  const int bid = blockIdx.x;
  const int h = bid >> 2, quarter = bid & 3;
  const int t = threadIdx.x, w = t >> 6, lane = t & 63;
  const int n16 = lane & 15, quad = lane >> 4;
  const int lb = lane & 3, lm = lane >> 2;

  const unsigned short* Gh = G + (size_t)h * 16384;
  short8 Av[4][2];
#pragma unroll
  for (int rt = 0; rt < 4; ++rt)
#pragma unroll
    for (int kt = 0; kt < 2; ++kt)
      Av[rt][kt] = *(const short8*)(Gh + (64+16*rt+n16)*128 + 64 + kt*32 + quad*8);

  unsigned short* X = X2[w];

#pragma unroll 1
  for (int cc = 0; cc < 4; ++cc) {
    const int q = quarter*16 + w*4 + cc;
    // stage U chunk -> [row][col] bf16
#pragma unroll
    for (int r = 0; r < 4; ++r) {
      const int m = r*16 + lm;
      const float4 lv = *(const float4*)(u + ((size_t)lb*SL + q*64 + m)*DM + 4*h);
      uint2 pk; pk.x = pack_bf16(lv.x, lv.y); pk.y = pack_bf16(lv.z, lv.w);
      *(uint2*)(X + 20*m + 4*lb) = pk;
    }
    // B-frags (scalar u16 reads, conflict-free by pad 20)
    short8 B[2];
#pragma unroll
    for (int kt = 0; kt < 2; ++kt) {
      union { short8 v; unsigned short s[8]; } fb;
#pragma unroll
      for (int j = 0; j < 8; ++j)
        fb.s[j] = X[(kt*32 + quad*8 + j)*20 + n16];
      B[kt] = fb.v;
    }
    // R = V@U -> bf16 C-frag slots
    char* slot = RS + (size_t)(h*64 + q) * 2048;
#pragma unroll
    for (int rt = 0; rt < 4; ++rt) {
      floatx4 acc = {0.f,0.f,0.f,0.f};
      acc = __builtin_amdgcn_mfma_f32_16x16x32_bf16(Av[rt][0], B[0], acc, 0,0,0);
      acc = __builtin_amdgcn_mfma_f32_16x16x32_bf16(Av[rt][1], B[1], acc, 0,0,0);
      uint2 pk; pk.x = pack_bf16(acc[0], acc[1]); pk.y = pack_bf16(acc[2], acc[3]);
      *(uint2*)(slot + rt*512 + lane*8) = pk;
    }
  }
}

// ------------------------------------------------------------- K3: scan --
// 1 wave/head, zero barriers. S'=T@S+R; transpose via wave-private LDS;
// stores S_q frags in-place over R slot (R_q already consumed).
__global__ __launch_bounds__(64) void scan_kernel(
    const unsigned short* __restrict__ G, char* __restrict__ RS)
{
  __shared__ unsigned short Xk[16 * 72];    // [col][row], stride 72 shorts

  const int h = blockIdx.x;
  const int lane = threadIdx.x;
  const int n16 = lane & 15, quad = lane >> 4;

  const unsigned short* Gh = G + (size_t)h * 16384;
  short8 At[4][2];
#pragma unroll
  for (int rt = 0; rt < 4; ++rt)
#pragma unroll
    for (int kt = 0; kt < 2; ++kt)
      At[rt][kt] = *(const short8*)(Gh + (64+16*rt+n16)*128 + kt*32 + quad*8);

  char* slot0 = RS + (size_t)h * 64 * 2048;

  floatx4 acc[4];
#pragma unroll
  for (int rt = 0; rt < 4; ++rt) acc[rt] = (floatx4){0.f,0.f,0.f,0.f};

  uint2 rb[4];
#pragma unroll
  for (int rt = 0; rt < 4; ++rt)
    rb[rt] = *(const uint2*)(slot0 + rt*512 + lane*8);

#pragma unroll 1
  for (int q = 0; q < NCHUNK; ++q) {
    // unpack R_q (forces vmcnt wait on the prefetched loads)
    floatx4 Cs[4];
#pragma unroll
    for (int rt = 0; rt < 4; ++rt) {
      Cs[rt][0] = bflo(rb[rt].x); Cs[rt][1] = bfhi(rb[rt].x);
      Cs[rt][2] = bflo(rb[rt].y); Cs[rt][3] = bfhi(rb[rt].y);
    }
    // prefetch R_{q+1}
    if (q < NCHUNK-1) {
#pragma unroll
      for (int rt = 0; rt < 4; ++rt)
        rb[rt] = *(const uint2*)(slot0 + (size_t)(q+1)*2048 + rt*512 + lane*8);
    }
    // S_q (C-layout acc) -> LDS [col][row] bf16
#pragma unroll
    for (int rt = 0; rt < 4; ++rt) {
      uint2 pk; pk.x = pack_bf16(acc[rt][0], acc[rt][1]);
      pk.y = pack_bf16(acc[rt][2], acc[rt][3]);
      *(uint2*)((char*)Xk + 144*n16 + 32*rt + 8*quad) = pk;
    }
    // B-frags of S_q
    short8 B0 = *(const short8*)((char*)Xk + 144*n16 + 16*quad);
    short8 B1 = *(const short8*)((char*)Xk + 144*n16 + 64 + 16*quad);
    // persist S_q frags for K4 (in-place over consumed R_q)
    *(short8*)(slot0 + (size_t)q*2048 + lane*16) = B0;
    *(short8*)(slot0 + (size_t)q*2048 + 1024 + lane*16) = B1;
    // S_{q+1} = T@S_q + R_q
#pragma unroll
    for (int rt = 0; rt < 4; ++rt) {
      floatx4 a0 = __builtin_amdgcn_mfma_f32_16x16x32_bf16(At[rt][0], B0, Cs[rt], 0,0,0);
      acc[rt]    = __builtin_amdgcn_mfma_f32_16x16x32_bf16(At[rt][1], B1, a0,     0,0,0);
    }
  }
}

// ------------------------------------------------------------- K4: out ---
// Y_q = W@S_q + Toep@U_q. Barrier-free; coalesced float4 stores via sY.
__global__ __launch_bounds__(256) void out_kernel(
    const float* __restrict__ u, const unsigned short* __restrict__ G,
    const char* __restrict__ RS, float* __restrict__ out)
{
  __shared__ unsigned short X2[4][64*20];
  __shared__ float sY[4][64*20];

  const int bid = blockIdx.x;
  const int h = bid >> 2, quarter = bid & 3;
  const int t = threadIdx.x, w = t >> 6, lane = t & 63;
  const int n16 = lane & 15, quad = lane >> 4;
  const int lb = lane & 3, lm = lane >> 2;

  const unsigned short* Gh = G + (size_t)h * 16384;
  short8 Aw[4][2], Ap[4][2];
#pragma unroll
  for (int rt = 0; rt < 4; ++rt)
#pragma unroll
    for (int kt = 0; kt < 2; ++kt) {
      Aw[rt][kt] = *(const short8*)(Gh + (16*rt+n16)*128 + kt*32 + quad*8);
      Ap[rt][kt] = *(const short8*)(Gh + (16*rt+n16)*128 + 64 + kt*32 + quad*8);
    }

  unsigned short* X = X2[w];
  float* sYw = sY[w];

#pragma unroll 1
  for (int cc = 0; cc < 4; ++cc) {
    const int q = quarter*16 + w*4 + cc;
    const char* slot = RS + (size_t)(h*64 + q) * 2048;

    // S_q frags (written by K3)
    short8 S0 = *(const short8*)(slot + lane*16);
    short8 S1 = *(const short8*)(slot + 1024 + lane*16);

    // stage U chunk
#pragma unroll
    for (int r = 0; r < 4; ++r) {
      const int m = r*16 + lm;
      const float4 lv = *(const float4*)(u + ((size_t)lb*SL + q*64 + m)*DM + 4*h);
      uint2 pk; pk.x = pack_bf16(lv.x, lv.y); pk.y = pack_bf16(lv.z, lv.w);
      *(uint2*)(X + 20*m + 4*lb) = pk;
    }
    short8 B[2];
#pragma unroll
    for (int kt = 0; kt < 2; ++kt) {
      union { short8 v; unsigned short s[8]; } fb;
#pragma unroll
      for (int j = 0; j < 8; ++j)
        fb.s[j] = X[(kt*32 + quad*8 + j)*20 + n16];
      B[kt] = fb.v;
    }

    // Y = Toep@U + W@S  (C-layout) -> sY transpose
#pragma unroll
    for (int rt = 0; rt < 4; ++rt) {
      floatx4 acc = {0.f,0.f,0.f,0.f};
      acc = __builtin_amdgcn_mfma_f32_16x16x32_bf16(Ap[rt][0], B[0], acc, 0,0,0);
      acc = __builtin_amdgcn_mfma_f32_16x16x32_bf16(Ap[rt][1], B[1], acc, 0,0,0);
      acc = __builtin_amdgcn_mfma_f32_16x16x32_bf16(Aw[rt][0], S0,   acc, 0,0,0);
      acc = __builtin_amdgcn_mfma_f32_16x16x32_bf16(Aw[rt][1], S1,   acc, 0,0,0);
#pragma unroll
      for (int r = 0; r < 4; ++r)
        sYw[(16*rt + 4*quad + r)*20 + n16] = acc[r];
    }

    // coalesced store
#pragma unroll
    for (int r = 0; r < 4; ++r) {
      const int row = r*16 + lm;
      const float4 yv = *(const float4*)(sYw + row*20 + lb*4);
      *(float4*)(out + ((size_t)lb*SL + q*64 + row)*DM + 4*h) = yv;
    }
  }
}

// ---------------------------------------------------------------- launch --
extern "C" void kernel_launch(void* const* d_in, const int* in_sizes, int n_in,
                              void* d_out, int out_size, void* d_ws, size_t ws_size,
                              hipStream_t stream)
{
  const float* u = (const float*)d_in[0];
  const float* a = (const float*)d_in[1];
  const float* b = (const float*)d_in[2];
  const float* c = (const float*)d_in[3];
  unsigned short* Gws = (unsigned short*)d_ws;        // [0, 8MB)
  char* RS = (char*)d_ws + ((size_t)8 << 20);         // [8MB, 40MB)
  float* out = (float*)d_out;

  prep_kernel<<<NKH, 128, 0, stream>>>(a, b, c, Gws);
  partial_kernel<<<NKH*4, 256, 0, stream>>>(u, Gws, RS);
  scan_kernel<<<NKH, 64, 0, stream>>>(Gws, RS);
  out_kernel<<<NKH*4, 256, 0, stream>>>(u, Gws, RS, out);
}